// Round 13
// baseline (302.879 us; speedup 1.0000x reference)
//
#include <hip/hip_runtime.h>

// DigitCapsules dynamic routing. Round-13 design:
//  - R12 post-mortem: per-pass floor (~5.9 us even with 8x fewer load bytes)
//    is the per-class __syncthreads: compiler drains vmcnt(0) at every
//    barrier (m97 lesson), so 30 passes = 30 full latency drains at 1
//    block/CU with nothing to overlap.
//  - FIX: 2 barriers per iteration instead of 10 (5 total, was 30):
//      pass A (no barriers): all 10 classes -> acc -> per-wave red[c] slots.
//        Loads pipeline freely across classes (partial vmcnt, AITER-style).
//        it0 also computes u_hat from W (16-row batches) and stores ut.
//      barrier; pass B: threads 0..159 squash all 10 classes -> vsh
//        (last iter: write out).
//      barrier; pass C (no barriers): agreement for all 10 classes by
//        RE-LOADING u from ut (94 MB/iter extra read -- cheap vs barrier
//        stalls; B's vmcnt(0) drain makes same-thread reload safe), update
//        blog, thread-local softmax for next iter. up[] regs dropped.
//  - Hazards: red WAR and vsh WAR protected by A|B and B|C barriers (pass C
//    never reads red; A' unreachable before B|C). blog slots thread-private.
//  - Kept: TPB=256 launch_bounds(256,1) (cap 256), blog LDS BPAD=11
//    (0 conflicts), f16 Wt[c][d][i] + v_dot2_f32_f16, ut[b][c][h][i] f16,
//    it0 softmax(0)=0.1 shortcut.

#define NCLS   10
#define NCAPS  1152
#define KDO    16
#define NIT    3
#define TPB    256
#define NJ     5            // j=0..3 all threads; j=4 only t<128
#define NWAVE  (TPB / 64)
#define BPAD   11

typedef _Float16 h2_t __attribute__((ext_vector_type(2)));
typedef unsigned u4 __attribute__((ext_vector_type(4)));

static __device__ __forceinline__ unsigned pack2h(float a, float b) {
    union { _Float16 h[2]; unsigned u; } p;
    p.h[0] = (_Float16)a;
    p.h[1] = (_Float16)b;
    return p.u;
}

static __device__ __forceinline__ float dot8h(u4 r, const unsigned* xh) {
    union { unsigned u; h2_t h; } w0, w1, w2, w3, a0, a1, a2, a3;
    w0.u = r.x; w1.u = r.y; w2.u = r.z; w3.u = r.w;
    a0.u = xh[0]; a1.u = xh[1]; a2.u = xh[2]; a3.u = xh[3];
#if __has_builtin(__builtin_amdgcn_fdot2)
    float acc = __builtin_amdgcn_fdot2(w0.h, a0.h, 0.f, false);
    acc = __builtin_amdgcn_fdot2(w1.h, a1.h, acc, false);
    acc = __builtin_amdgcn_fdot2(w2.h, a2.h, acc, false);
    acc = __builtin_amdgcn_fdot2(w3.h, a3.h, acc, false);
    return acc;
#else
    return (float)w0.h.x * (float)a0.h.x + (float)w0.h.y * (float)a0.h.y
         + (float)w1.h.x * (float)a1.h.x + (float)w1.h.y * (float)a1.h.y
         + (float)w2.h.x * (float)a2.h.x + (float)w2.h.y * (float)a2.h.y
         + (float)w3.h.x * (float)a3.h.x + (float)w3.h.y * (float)a3.h.y;
#endif
}

static __device__ __forceinline__ float dot2h(unsigned a, unsigned b, float acc) {
    union { unsigned u; h2_t h; } pa, pb;
    pa.u = a; pb.u = b;
#if __has_builtin(__builtin_amdgcn_fdot2)
    return __builtin_amdgcn_fdot2(pa.h, pb.h, acc, false);
#else
    return acc + (float)pa.h.x * (float)pb.h.x + (float)pa.h.y * (float)pb.h.y;
#endif
}

// Wt[c][d][i] : u4 holding f16 W[c,i,0,d,k] for k=0..7
__global__ __launch_bounds__(256)
void pack_W_f16(const float4* __restrict__ W4, u4* __restrict__ Wt) {
    int tid = blockIdx.x * blockDim.x + threadIdx.x;   // (c*NCAPS+i)*KDO + d
    if (tid >= NCLS * NCAPS * KDO) return;
    int d = tid & 15;
    int rest = tid >> 4;
    int i = rest % NCAPS;
    int c = rest / NCAPS;
    float4 a = W4[2 * tid];
    float4 b = W4[2 * tid + 1];
    u4 o;
    o.x = pack2h(a.x, a.y);
    o.y = pack2h(a.z, a.w);
    o.z = pack2h(b.x, b.y);
    o.w = pack2h(b.z, b.w);
    Wt[(size_t)(c * KDO + d) * NCAPS + i] = o;
}

__global__ __launch_bounds__(TPB, 1)          // cap 256 VGPR at TPB=256 (measured)
void caps_routing_v13(const u4* __restrict__ Wt,    // [C][KDO][I] f16x8
                      u4* __restrict__ ut,          // [B][C][2][I] u_hat f16x8
                      const float* __restrict__ x,  // [B, I, 8]
                      float* __restrict__ out)      // [B, C, 1, KDO]
{
    const int b    = blockIdx.x;
    const int t    = threadIdx.x;
    const int lane = t & 63;
    const int wave = t >> 6;

    __shared__ float blogL[NCAPS * BPAD];            // 50688 B
    __shared__ float red[NCLS][NWAVE * KDO];         // 2560 B
    __shared__ float vsh[NCLS * KDO];                // 640 B

    // ---- x[b, ii, :] packed f16 in registers ----
    unsigned xh[NJ][4];
    const float4* x4 = reinterpret_cast<const float4*>(x) + (size_t)b * NCAPS * 2;
    #pragma unroll
    for (int j = 0; j < NJ; ++j) {
        int ii = t + TPB * j;
        if (ii < NCAPS) {
            float4 x0 = x4[2 * ii];
            float4 x1 = x4[2 * ii + 1];
            xh[j][0] = pack2h(x0.x, x0.y);
            xh[j][1] = pack2h(x0.z, x0.w);
            xh[j][2] = pack2h(x1.x, x1.y);
            xh[j][3] = pack2h(x1.z, x1.w);
        }
    }

    float* outb = out + (size_t)b * NCLS * KDO;
    u4* utb = ut + (size_t)b * NCLS * 2 * NCAPS;
    float sm[NJ], sid[NJ];                           // softmax state (from pass C)

    #pragma unroll 1
    for (int it = 0; it < NIT; ++it) {
        const bool first = (it == 0);
        const bool last  = (it == NIT - 1);

        // ================= pass A : acc all 10 classes, NO barriers =========
        #pragma unroll 1
        for (int c = 0; c < NCLS; ++c) {
            float acc[KDO];
            #pragma unroll
            for (int d = 0; d < KDO; ++d) acc[d] = 0.f;

            if (first) {
                // W sweep (16-row batch) + ut store, weight = 1 (scale 0.1 in B)
                #pragma unroll
                for (int j = 0; j < NJ; ++j) {
                    int ii = t + TPB * j;
                    if (ii < NCAPS) {
                        const u4* base = Wt + (size_t)c * KDO * NCAPS + ii;
                        u4 r[KDO];
                        #pragma unroll
                        for (int d = 0; d < KDO; ++d)
                            r[d] = __builtin_nontemporal_load(base + (size_t)d * NCAPS);
                        u4 h0, h1;
                        #pragma unroll
                        for (int dp = 0; dp < 8; ++dp) {
                            float u0 = dot8h(r[2 * dp],     xh[j]);
                            float u1 = dot8h(r[2 * dp + 1], xh[j]);
                            acc[2 * dp]     += u0;
                            acc[2 * dp + 1] += u1;
                            unsigned pk = pack2h(u0, u1);
                            if (dp < 4) { ((unsigned*)&h0)[dp] = pk; }
                            else        { ((unsigned*)&h1)[dp - 4] = pk; }
                        }
                        utb[((size_t)c * 2 + 0) * NCAPS + ii] = h0;
                        utb[((size_t)c * 2 + 1) * NCAPS + ii] = h1;
                    }
                }
            } else {
                // u from ut cache, weighted by softmax
                #pragma unroll
                for (int j = 0; j < NJ; ++j) {
                    int ii = t + TPB * j;
                    if (ii < NCAPS) {
                        u4 h0 = utb[((size_t)c * 2 + 0) * NCAPS + ii];
                        u4 h1 = utb[((size_t)c * 2 + 1) * NCAPS + ii];
                        float w = __expf(blogL[ii * BPAD + c] - sm[j]) * sid[j];
                        #pragma unroll
                        for (int dp = 0; dp < 8; ++dp) {
                            union { unsigned u; h2_t h; } p;
                            p.u = (dp < 4) ? ((unsigned*)&h0)[dp] : ((unsigned*)&h1)[dp - 4];
                            acc[2 * dp]     += w * (float)p.h.x;
                            acc[2 * dp + 1] += w * (float)p.h.y;
                        }
                    }
                }
            }

            // per-wave reduce -> red[c] (own slots, no sync needed)
            #pragma unroll
            for (int d = 0; d < KDO; ++d) {
                float v = acc[d];
                v += __shfl_xor(v, 32, 64);
                v += __shfl_xor(v, 16, 64);
                v += __shfl_xor(v,  8, 64);
                v += __shfl_xor(v,  4, 64);
                v += __shfl_xor(v,  2, 64);
                v += __shfl_xor(v,  1, 64);
                if (lane == 0) red[c][wave * KDO + d] = v;
            }
        }
        __syncthreads();                             // barrier 1 (drains A loads/stores)

        // ================= pass B : squash all 10 classes ===================
        if (t < NCLS * KDO) {
            int c = t >> 4;
            int d = t & 15;
            float s = 0.f;
            #pragma unroll
            for (int w = 0; w < NWAVE; ++w) s += red[c][w * KDO + d];
            if (first) s *= 0.1f;                    // softmax(0) = 1/10
            float nsq = s * s;
            nsq += __shfl_xor(nsq, 8, 16);
            nsq += __shfl_xor(nsq, 4, 16);
            nsq += __shfl_xor(nsq, 2, 16);
            nsq += __shfl_xor(nsq, 1, 16);
            float sc = sqrtf(nsq) / (1.f + nsq);     // (nsq/(1+nsq))/sqrt(nsq)
            float vv = s * sc;
            vsh[t] = vv;
            if (last) outb[t] = vv;
        }
        if (last) break;                             // it2: done after B
        __syncthreads();                             // barrier 2 (publish vsh)

        // ====== pass C : agreement (re-load ut) + blog + softmax, no barrier =
        #pragma unroll 1
        for (int c = 0; c < NCLS; ++c) {
            unsigned vp[8];
            #pragma unroll
            for (int dp = 0; dp < 8; ++dp)
                vp[dp] = pack2h(vsh[c * KDO + 2 * dp], vsh[c * KDO + 2 * dp + 1]);
            #pragma unroll
            for (int j = 0; j < NJ; ++j) {
                int ii = t + TPB * j;
                if (ii < NCAPS) {
                    u4 h0 = utb[((size_t)c * 2 + 0) * NCAPS + ii];
                    u4 h1 = utb[((size_t)c * 2 + 1) * NCAPS + ii];
                    float a = 0.f;
                    #pragma unroll
                    for (int dp = 0; dp < 8; ++dp) {
                        unsigned pk = (dp < 4) ? ((unsigned*)&h0)[dp]
                                               : ((unsigned*)&h1)[dp - 4];
                        a = dot2h(pk, vp[dp], a);
                    }
                    if (first) blogL[ii * BPAD + c] = a;
                    else       blogL[ii * BPAD + c] += a;
                }
            }
        }
        // thread-local softmax for next iteration (blog slots thread-private)
        #pragma unroll
        for (int j = 0; j < NJ; ++j) {
            int ii = t + TPB * j;
            if (ii < NCAPS) {
                float bl[NCLS];
                #pragma unroll
                for (int c = 0; c < NCLS; ++c) bl[c] = blogL[ii * BPAD + c];
                float m = bl[0];
                #pragma unroll
                for (int c = 1; c < NCLS; ++c) m = fmaxf(m, bl[c]);
                float den = 0.f;
                #pragma unroll
                for (int c = 0; c < NCLS; ++c) den += __expf(bl[c] - m);
                sm[j]  = m;
                sid[j] = 1.f / den;
            }
        }
        // no barrier: next pass A touches only thread-private blog + own red slots
    }
}

// ---- fallback (no/small workspace): round-1 fp32 kernel, proven correct ----
__global__ __launch_bounds__(256, 2)
void caps_routing_fb(const float* __restrict__ x, const float* __restrict__ W,
                     float* __restrict__ out)
{
    const int b    = blockIdx.x;
    const int t    = threadIdx.x;
    const int lane = t & 63;
    const int wave = t >> 6;
    __shared__ float v_prev[NCLS * KDO];
    __shared__ float redf[NCLS * 4 * KDO];
    float4 xr[5][2];
    const float4* x4 = reinterpret_cast<const float4*>(x + (size_t)b * NCAPS * 8);
    #pragma unroll
    for (int j = 0; j < 5; ++j) {
        int i = t + 256 * j;
        if (i < NCAPS) { xr[j][0] = x4[2 * i]; xr[j][1] = x4[2 * i + 1]; }
    }
    float blog[5][NCLS];
    #pragma unroll
    for (int j = 0; j < 5; ++j)
        #pragma unroll
        for (int c = 0; c < NCLS; ++c) blog[j][c] = 0.f;
    const float4* W4 = reinterpret_cast<const float4*>(W);
    for (int it = 0; it < NIT; ++it) {
        if (it > 0) {
            for (int c = 0; c < NCLS; ++c) {
                float vp[KDO];
                #pragma unroll
                for (int d = 0; d < KDO; ++d) vp[d] = v_prev[c * KDO + d];
                #pragma unroll
                for (int j = 0; j < 5; ++j) {
                    int i = t + 256 * j;
                    if (i < NCAPS) {
                        size_t wb = (size_t)(c * NCAPS + i) * 32;
                        float a = 0.f;
                        #pragma unroll
                        for (int d = 0; d < KDO; ++d) {
                            float4 w0 = W4[wb + 2 * d]; float4 w1 = W4[wb + 2 * d + 1];
                            float u = w0.x*xr[j][0].x + w0.y*xr[j][0].y + w0.z*xr[j][0].z
                                    + w0.w*xr[j][0].w + w1.x*xr[j][1].x + w1.y*xr[j][1].y
                                    + w1.z*xr[j][1].z + w1.w*xr[j][1].w;
                            a += u * vp[d];
                        }
                        blog[j][c] += a;
                    }
                }
            }
        }
        float sm2[5], sid2[5];
        #pragma unroll
        for (int j = 0; j < 5; ++j) {
            int i = t + 256 * j;
            if (i < NCAPS) {
                float m = blog[j][0];
                #pragma unroll
                for (int c = 1; c < NCLS; ++c) m = fmaxf(m, blog[j][c]);
                float den = 0.f;
                #pragma unroll
                for (int c = 0; c < NCLS; ++c) den += __expf(blog[j][c] - m);
                sm2[j] = m; sid2[j] = 1.f / den;
            }
        }
        for (int c = 0; c < NCLS; ++c) {
            float acc[KDO];
            #pragma unroll
            for (int d = 0; d < KDO; ++d) acc[d] = 0.f;
            #pragma unroll
            for (int j = 0; j < 5; ++j) {
                int i = t + 256 * j;
                if (i < NCAPS) {
                    float w = __expf(blog[j][c] - sm2[j]) * sid2[j];
                    size_t wb = (size_t)(c * NCAPS + i) * 32;
                    #pragma unroll
                    for (int d = 0; d < KDO; ++d) {
                        float4 w0 = W4[wb + 2 * d]; float4 w1 = W4[wb + 2 * d + 1];
                        float u = w0.x*xr[j][0].x + w0.y*xr[j][0].y + w0.z*xr[j][0].z
                                + w0.w*xr[j][0].w + w1.x*xr[j][1].x + w1.y*xr[j][1].y
                                + w1.z*xr[j][1].z + w1.w*xr[j][1].w;
                        acc[d] += w * u;
                    }
                }
            }
            #pragma unroll
            for (int d = 0; d < KDO; ++d) {
                float v = acc[d];
                v += __shfl_xor(v, 32, 64); v += __shfl_xor(v, 16, 64);
                v += __shfl_xor(v,  8, 64); v += __shfl_xor(v,  4, 64);
                v += __shfl_xor(v,  2, 64); v += __shfl_xor(v,  1, 64);
                if (lane == 0) redf[(c * 4 + wave) * KDO + d] = v;
            }
        }
        __syncthreads();
        if (t < NCLS * KDO) {
            int c = t >> 4, d = t & 15;
            float s = redf[(c*4+0)*KDO+d] + redf[(c*4+1)*KDO+d]
                    + redf[(c*4+2)*KDO+d] + redf[(c*4+3)*KDO+d];
            float nsq = s * s;
            nsq += __shfl_xor(nsq, 8, 16); nsq += __shfl_xor(nsq, 4, 16);
            nsq += __shfl_xor(nsq, 2, 16); nsq += __shfl_xor(nsq, 1, 16);
            float scale = sqrtf(nsq) / (1.f + nsq);
            float vv = s * scale;
            v_prev[t] = vv;
            if (it == NIT - 1) out[(size_t)b * NCLS * KDO + t] = vv;
        }
        __syncthreads();
    }
}

extern "C" void kernel_launch(void* const* d_in, const int* in_sizes, int n_in,
                              void* d_out, int out_size, void* d_ws, size_t ws_size,
                              hipStream_t stream) {
    const float* x = (const float*)d_in[0];              // [256, 1152, 8] fp32
    const float4* W4 = (const float4*)d_in[1];           // [10, 1152, 1, 16, 8] fp32
    float* out = (float*)d_out;                          // [256, 10, 1, 16] fp32
    (void)in_sizes; (void)n_in; (void)out_size;

    const int B = 256;
    const size_t wt_bytes = (size_t)NCLS * KDO * NCAPS * sizeof(u4);        // 2.95 MB
    const size_t ut_bytes = (size_t)B * NCLS * 2 * NCAPS * sizeof(u4);      // 94.4 MB
    if (ws_size >= wt_bytes + ut_bytes) {
        u4* Wt = (u4*)d_ws;
        u4* ut = (u4*)((char*)d_ws + wt_bytes);
        int total = NCLS * NCAPS * KDO;
        pack_W_f16<<<dim3((total + 255) / 256), dim3(256), 0, stream>>>(W4, Wt);
        caps_routing_v13<<<dim3(B), dim3(TPB), 0, stream>>>(Wt, ut, x, out);
    } else {
        caps_routing_fb<<<dim3(B), dim3(256), 0, stream>>>(x, (const float*)d_in[1], out);
    }
}